// Round 5
// baseline (1562.320 us; speedup 1.0000x reference)
//
#include <hip/hip_runtime.h>
#include <hip/hip_bf16.h>
#include <hip/hip_cooperative_groups.h>

namespace cg = cooperative_groups;

#define VOCAB 50000
#define EMBD  512
#define HID   1024
#define NB    256
#define SEQW  26
#define MTOT  (SEQW * NB)   /* 6656 */
#define NGATE (4 * HID)     /* 4096 */

typedef short short8 __attribute__((ext_vector_type(8)));
typedef float f32x4  __attribute__((ext_vector_type(4)));

__device__ __forceinline__ unsigned short f2bf_bits(float x) {
    union { __hip_bfloat16 b; unsigned short u; } cv;
    cv.b = __float2bfloat16(x);
    return cv.u;
}

__device__ __forceinline__ void split_bf16(float x, unsigned short& hi, unsigned short& lo) {
    __hip_bfloat16 h = __float2bfloat16(x);
    float hf = __bfloat162float(h);
    hi = f2bf_bits(x);
    lo = f2bf_bits(x - hf);
}

// ---------------- init: zero h0 (hi/lo) ----------------
__global__ void init_kernel(unsigned short* __restrict__ hHi0,
                            unsigned short* __restrict__ hLo0) {
    int idx = blockIdx.x * blockDim.x + threadIdx.x;
    hHi0[idx] = 0;
    hLo0[idx] = 0;
}

// ---------------- embedding: gather + tanh -> bf16 hi/lo ----------------
__global__ void embed_kernel(const int* __restrict__ qv,
                             const float* __restrict__ Wemb,
                             unsigned short* __restrict__ eHi,
                             unsigned short* __restrict__ eLo) {
    int pair = blockIdx.x * 4 + (threadIdx.x >> 6);
    int t = pair / NB;
    int b = pair % NB;
    int tok = qv[b * SEQW + t];
    int lane = threadIdx.x & 63;
    size_t base = (size_t)pair * EMBD;
    if (tok > 0) {
        int v = tok - 1;
        for (int e = lane; e < EMBD; e += 64) {
            float x = Wemb[(size_t)e * VOCAB + v];
            float y = tanhf(x);
            unsigned short hi, lo;
            split_bf16(y, hi, lo);
            eHi[base + e] = hi;
            eLo[base + e] = lo;
        }
    } else {
        for (int e = lane; e < EMBD; e += 64) {
            eHi[base + e] = 0;
            eLo[base + e] = 0;
        }
    }
}

// ---------------- weight split (separate ih / hh) + bias sum ----------------
__global__ void convw_kernel(const float* __restrict__ Wih,
                             const float* __restrict__ Whh,
                             const float* __restrict__ b_ih,
                             const float* __restrict__ b_hh,
                             unsigned short* __restrict__ ihHi,
                             unsigned short* __restrict__ ihLo,
                             unsigned short* __restrict__ hhHi,
                             unsigned short* __restrict__ hhLo,
                             float* __restrict__ bsum) {
    int j = blockIdx.x; // 0..4095
    if (threadIdx.x == 0) bsum[j] = b_ih[j] + b_hh[j];
    for (int col = threadIdx.x; col < EMBD; col += blockDim.x) {
        unsigned short hi, lo;
        split_bf16(Wih[(size_t)j * EMBD + col], hi, lo);
        ihHi[(size_t)j * EMBD + col] = hi;
        ihLo[(size_t)j * EMBD + col] = lo;
    }
    for (int col = threadIdx.x; col < HID; col += blockDim.x) {
        unsigned short hi, lo;
        split_bf16(Whh[(size_t)j * HID + col], hi, lo);
        hhHi[(size_t)j * HID + col] = hi;
        hhLo[(size_t)j * HID + col] = lo;
    }
}

// ---------------- pre-GEMM: G0s[t][ct][b][32] = emb @ Wih^T (3-term bf16) ---
// 1664 blocks 1-D: xcd = id&7 owns 4 col-panels (pc = xcd*4 + (lid&3)),
// pm = lid>>2 iterates M; col-panels iterate fastest -> A chunk (256KB) hot in
// L2 across the 4 consecutive blocks; B panel (1MB/XCD slice) L2-resident.
__global__ __launch_bounds__(512, 1) void pregemm_kernel(
    const unsigned short* __restrict__ eHi, const unsigned short* __restrict__ eLo,
    const unsigned short* __restrict__ ihHi, const unsigned short* __restrict__ ihLo,
    float* __restrict__ G0s)
{
    int id = blockIdx.x;
    int xcd = id & 7;
    int lid = id >> 3;
    int pc = xcd * 4 + (lid & 3);   // 0..31 col tile (128 gate-cols: 32 jh x 4 g)
    int pm = lid >> 2;              // 0..51 row tile (128 rows)
    int jh0 = pc * 32;
    int m0  = pm * 128;

    int wave = threadIdx.x >> 6;
    int g  = wave & 3;
    int mh = wave >> 2;
    int lane = threadIdx.x & 63;
    int col16 = lane & 15;
    int g4 = lane >> 4;

    f32x4 acc[4][2];
    #pragma unroll
    for (int fm = 0; fm < 4; ++fm)
        #pragma unroll
        for (int fn = 0; fn < 2; ++fn)
            acc[fm][fn] = (f32x4){0.f, 0.f, 0.f, 0.f};

    const unsigned short* aHiP[4];
    const unsigned short* aLoP[4];
    #pragma unroll
    for (int fm = 0; fm < 4; ++fm) {
        size_t row = (size_t)(m0 + mh * 64 + fm * 16 + col16);
        aHiP[fm] = eHi + row * EMBD + 8 * g4;
        aLoP[fm] = eLo + row * EMBD + 8 * g4;
    }
    const unsigned short* bHiP[2];
    const unsigned short* bLoP[2];
    #pragma unroll
    for (int fn = 0; fn < 2; ++fn) {
        size_t row = (size_t)(g * HID + jh0 + fn * 16 + col16);
        bHiP[fn] = ihHi + row * EMBD + 8 * g4;
        bLoP[fn] = ihLo + row * EMBD + 8 * g4;
    }

    #pragma unroll
    for (int kk = 0; kk < EMBD; kk += 32) {
        short8 bH[2], bL[2];
        #pragma unroll
        for (int fn = 0; fn < 2; ++fn) {
            bH[fn] = *(const short8*)(bHiP[fn] + kk);
            bL[fn] = *(const short8*)(bLoP[fn] + kk);
        }
        #pragma unroll
        for (int fm = 0; fm < 4; ++fm) {
            short8 aH = *(const short8*)(aHiP[fm] + kk);
            short8 aL = *(const short8*)(aLoP[fm] + kk);
            #pragma unroll
            for (int fn = 0; fn < 2; ++fn) {
                acc[fm][fn] = __builtin_amdgcn_mfma_f32_16x16x32_bf16(aH, bH[fn], acc[fm][fn], 0, 0, 0);
                acc[fm][fn] = __builtin_amdgcn_mfma_f32_16x16x32_bf16(aH, bL[fn], acc[fm][fn], 0, 0, 0);
                acc[fm][fn] = __builtin_amdgcn_mfma_f32_16x16x32_bf16(aL, bH[fn], acc[fm][fn], 0, 0, 0);
            }
        }
    }

    // write to G0s[t][ct 0..127][b 0..255][cidx 0..31], cidx = g*8 + jj
    #pragma unroll
    for (int fm = 0; fm < 4; ++fm)
        #pragma unroll
        for (int fn = 0; fn < 2; ++fn)
            #pragma unroll
            for (int r = 0; r < 4; ++r) {
                int row = m0 + mh * 64 + fm * 16 + g4 * 4 + r;
                int t = row >> 8, b = row & 255;
                int jhc = jh0 + fn * 16 + col16;
                int ct = jhc >> 3, jj = jhc & 7;
                G0s[(((size_t)t * 128 + ct) * 256 + b) * 32 + g * 8 + jj] = acc[fm][fn][r];
            }
}

// ---------------- persistent LSTM: Whh lives in LDS for all 26 steps --------
// 256 blocks x 512 threads, 1 block/CU. Block: ct = coltile (8 jh-cols x 4
// gates = 32 gate-cols, XCD-clustered), mt = batch tile (BM=128).
// LDS: Whh hi (64KB, XOR-swizzled) + Whh lo (64KB) + gbuf (18KB) = 146KB.
// Wave w owns Mfrag w (16 rows) x both Nfrags; c-state in registers.
// grid.sync() between steps: invalidates L2 but NOT LDS -> weights persist.
__global__ __launch_bounds__(512, 1) void lstm_persist(
    const unsigned short* __restrict__ hhHi, const unsigned short* __restrict__ hhLo,
    unsigned short* __restrict__ h0Hi, unsigned short* __restrict__ h0Lo,
    unsigned short* __restrict__ h1Hi, unsigned short* __restrict__ h1Lo,
    const float* __restrict__ G0s, const float* __restrict__ bsum,
    float* __restrict__ out)
{
    cg::grid_group grid = cg::this_grid();
    extern __shared__ char smem[];
    // [0,65536): whh hi, [65536,131072): whh lo, [131072,149504): gbuf[128][36]
    float* gbuf = (float*)(smem + 131072);

    int bx = blockIdx.x;
    int ct = (bx & 7) * 16 + ((bx >> 3) & 15);  // 0..127
    int mt = bx >> 7;                           // 0..1
    int m0 = mt * 128;
    int jh0 = ct * 8;

    int tid = threadIdx.x;
    int w = tid >> 6;
    int lane = tid & 63;
    int row16 = lane & 15;
    int g4 = lane >> 4;

    // ---- stage Whh slice into LDS (once), XOR-swizzled ----
    // lds row r = g*8 + jj  <->  global row g*HID + jh0 + jj ; row bytes 2048.
    for (int i = tid; i < 32 * 128; i += 512) {
        int r = i >> 7;
        int byteInRow = (i & 127) << 4;
        int g = r >> 3, jj = r & 7;
        size_t grow = (size_t)(g * HID + jh0 + jj) * HID;
        int dst = r * 2048 + (byteInRow ^ ((r & 7) << 4));
        *(short8*)(smem + dst) =
            *(const short8*)((const char*)(hhHi + grow) + byteInRow);
        *(short8*)(smem + 65536 + dst) =
            *(const short8*)((const char*)(hhLo + grow) + byteInRow);
    }

    // epilogue cells: idx = tid + u*512 -> (ml = idx>>3, jj = idx&7)
    float bs[2][4];
    #pragma unroll
    for (int u = 0; u < 2; ++u) {
        int jj = (tid + u * 512) & 7;
        #pragma unroll
        for (int g = 0; g < 4; ++g)
            bs[u][g] = bsum[g * HID + jh0 + jj];
    }
    float cReg[2] = {0.f, 0.f};

    __syncthreads();

    int bbase = row16 * 2048;
    int bxor = (row16 & 7) << 4;

    for (int t = 0; t < SEQW; ++t) {
        const unsigned short* hInHi = (t & 1) ? h1Hi : h0Hi;
        const unsigned short* hInLo = (t & 1) ? h1Lo : h0Lo;
        unsigned short* hOutHi = (t & 1) ? h0Hi : h1Hi;
        unsigned short* hOutLo = (t & 1) ? h0Lo : h1Lo;

        // prefetch G0 contributions for this step's epilogue (hides L3 latency)
        float g0v[2][4];
        const float* G0t = G0s + ((size_t)t * 128 + ct) * (256 * 32);
        #pragma unroll
        for (int u = 0; u < 2; ++u) {
            int idx = tid + u * 512;
            int ml = idx >> 3, jj = idx & 7;
            const float* p = G0t + (size_t)(m0 + ml) * 32 + jj;
            #pragma unroll
            for (int g = 0; g < 4; ++g) g0v[u][g] = p[g * 8];
        }

        const unsigned short* aHi = hInHi + (size_t)(m0 + w * 16 + row16) * HID + 8 * g4;
        const unsigned short* aLo = hInLo + (size_t)(m0 + w * 16 + row16) * HID + 8 * g4;

        f32x4 acc0 = {0.f, 0.f, 0.f, 0.f};
        f32x4 acc1 = {0.f, 0.f, 0.f, 0.f};

        #pragma unroll
        for (int kk = 0; kk < 32; ++kk) {
            short8 aH = *(const short8*)(aHi + kk * 32);
            short8 aL = *(const short8*)(aLo + kk * 32);
            int boff = ((kk * 64 + g4 * 16) ^ bxor);
            short8 bH0 = *(const short8*)(smem + bbase + boff);
            short8 bL0 = *(const short8*)(smem + 65536 + bbase + boff);
            short8 bH1 = *(const short8*)(smem + 32768 + bbase + boff);
            short8 bL1 = *(const short8*)(smem + 65536 + 32768 + bbase + boff);
            acc0 = __builtin_amdgcn_mfma_f32_16x16x32_bf16(aH, bH0, acc0, 0, 0, 0);
            acc0 = __builtin_amdgcn_mfma_f32_16x16x32_bf16(aH, bL0, acc0, 0, 0, 0);
            acc0 = __builtin_amdgcn_mfma_f32_16x16x32_bf16(aL, bH0, acc0, 0, 0, 0);
            acc1 = __builtin_amdgcn_mfma_f32_16x16x32_bf16(aH, bH1, acc1, 0, 0, 0);
            acc1 = __builtin_amdgcn_mfma_f32_16x16x32_bf16(aH, bL1, acc1, 0, 0, 0);
            acc1 = __builtin_amdgcn_mfma_f32_16x16x32_bf16(aL, bH1, acc1, 0, 0, 0);
        }

        // scatter gate partials: C/D row = g4*4+r, col = row16 (B-row = cidx)
        #pragma unroll
        for (int r = 0; r < 4; ++r) {
            gbuf[(w * 16 + g4 * 4 + r) * 36 + row16] = acc0[r];
            gbuf[(w * 16 + g4 * 4 + r) * 36 + 16 + row16] = acc1[r];
        }
        __syncthreads();

        #pragma unroll
        for (int u = 0; u < 2; ++u) {
            int idx = tid + u * 512;
            int ml = idx >> 3, jj = idx & 7;
            float gi  = gbuf[ml * 36 + jj]      + g0v[u][0] + bs[u][0];
            float gf  = gbuf[ml * 36 + 8 + jj]  + g0v[u][1] + bs[u][1];
            float gg_ = gbuf[ml * 36 + 16 + jj] + g0v[u][2] + bs[u][2];
            float go  = gbuf[ml * 36 + 24 + jj] + g0v[u][3] + bs[u][3];
            float si = 1.0f / (1.0f + expf(-gi));
            float sf = 1.0f / (1.0f + expf(-gf));
            float so = 1.0f / (1.0f + expf(-go));
            float tg = tanhf(gg_);
            float cN = sf * cReg[u] + si * tg;
            float hN = so * tanhf(cN);
            cReg[u] = cN;
            size_t p = (size_t)(m0 + ml) * HID + jh0 + jj;
            unsigned short hh, hl;
            split_bf16(hN, hh, hl);
            hOutHi[p] = hh;
            hOutLo[p] = hl;
            if (t == SEQW - 1) out[p] = hN;
        }

        if (t < SEQW - 1) grid.sync();
    }
}

extern "C" void kernel_launch(void* const* d_in, const int* in_sizes, int n_in,
                              void* d_out, int out_size, void* d_ws, size_t ws_size,
                              hipStream_t stream) {
    const int*   qv   = (const int*)d_in[0];
    const float* Wemb = (const float*)d_in[2];
    const float* Wih  = (const float*)d_in[3];
    const float* Whh  = (const float*)d_in[4];
    const float* b_ih = (const float*)d_in[5];
    const float* b_hh = (const float*)d_in[6];
    float* out = (float*)d_out;

    char* ws = (char*)d_ws;
    size_t off = 0;
    unsigned short* embHi = (unsigned short*)(ws + off); off += (size_t)MTOT * EMBD * 2;
    unsigned short* embLo = (unsigned short*)(ws + off); off += (size_t)MTOT * EMBD * 2;
    unsigned short* ihHi  = (unsigned short*)(ws + off); off += (size_t)NGATE * EMBD * 2;
    unsigned short* ihLo  = (unsigned short*)(ws + off); off += (size_t)NGATE * EMBD * 2;
    unsigned short* hhHi  = (unsigned short*)(ws + off); off += (size_t)NGATE * HID * 2;
    unsigned short* hhLo  = (unsigned short*)(ws + off); off += (size_t)NGATE * HID * 2;
    unsigned short* h0Hi  = (unsigned short*)(ws + off); off += (size_t)NB * HID * 2;
    unsigned short* h0Lo  = (unsigned short*)(ws + off); off += (size_t)NB * HID * 2;
    unsigned short* h1Hi  = (unsigned short*)(ws + off); off += (size_t)NB * HID * 2;
    unsigned short* h1Lo  = (unsigned short*)(ws + off); off += (size_t)NB * HID * 2;
    float* bsum           = (float*)(ws + off);          off += (size_t)NGATE * 4;
    float* G0s            = (float*)(ws + off);          off += (size_t)MTOT * NGATE * 4; // 109 MB

    init_kernel<<<NB * HID / 256, 256, 0, stream>>>(h0Hi, h0Lo);
    embed_kernel<<<MTOT / 4, 256, 0, stream>>>(qv, Wemb, embHi, embLo);
    convw_kernel<<<NGATE, 256, 0, stream>>>(Wih, Whh, b_ih, b_hh,
                                            ihHi, ihLo, hhHi, hhLo, bsum);
    pregemm_kernel<<<1664, 512, 0, stream>>>(embHi, embLo, ihHi, ihLo, G0s);

    void* kargs[] = {
        (void*)&hhHi, (void*)&hhLo,
        (void*)&h0Hi, (void*)&h0Lo, (void*)&h1Hi, (void*)&h1Lo,
        (void*)&G0s, (void*)&bsum, (void*)&out
    };
    hipLaunchCooperativeKernel((const void*)lstm_persist, dim3(256), dim3(512),
                               kargs, 149504, stream);
}

// Round 6
// 1485.068 us; speedup vs baseline: 1.0520x; 1.0520x over previous
//
#include <hip/hip_runtime.h>
#include <hip/hip_bf16.h>

#define VOCAB 50000
#define EMBD  512
#define HID   1024
#define NB    256
#define SEQW  26
#define MTOT  (SEQW * NB)   /* 6656 */
#define NGATE (4 * HID)     /* 4096 */
#define GRPBLK 128          /* blocks per barrier group */

typedef short short8 __attribute__((ext_vector_type(8)));
typedef float f32x4  __attribute__((ext_vector_type(4)));

__device__ __forceinline__ unsigned short f2bf_bits(float x) {
    union { __hip_bfloat16 b; unsigned short u; } cv;
    cv.b = __float2bfloat16(x);
    return cv.u;
}

__device__ __forceinline__ void split_bf16(float x, unsigned short& hi, unsigned short& lo) {
    __hip_bfloat16 h = __float2bfloat16(x);
    float hf = __bfloat162float(h);
    hi = f2bf_bits(x);
    lo = f2bf_bits(x - hf);
}

// ---------------- init: zero h0 (hi/lo) + barrier state ----------------
__global__ void init_kernel(unsigned short* __restrict__ hHi0,
                            unsigned short* __restrict__ hLo0,
                            unsigned int* __restrict__ barrier) {
    int idx = blockIdx.x * blockDim.x + threadIdx.x;
    hHi0[idx] = 0;
    hLo0[idx] = 0;
    if (blockIdx.x == 0 && threadIdx.x < 128) barrier[threadIdx.x] = 0;
}

// ---------------- embedding: gather + tanh -> bf16 hi/lo ----------------
__global__ void embed_kernel(const int* __restrict__ qv,
                             const float* __restrict__ Wemb,
                             unsigned short* __restrict__ eHi,
                             unsigned short* __restrict__ eLo) {
    int pair = blockIdx.x * 4 + (threadIdx.x >> 6);
    int t = pair / NB;
    int b = pair % NB;
    int tok = qv[b * SEQW + t];
    int lane = threadIdx.x & 63;
    size_t base = (size_t)pair * EMBD;
    if (tok > 0) {
        int v = tok - 1;
        for (int e = lane; e < EMBD; e += 64) {
            float x = Wemb[(size_t)e * VOCAB + v];
            float y = tanhf(x);
            unsigned short hi, lo;
            split_bf16(y, hi, lo);
            eHi[base + e] = hi;
            eLo[base + e] = lo;
        }
    } else {
        for (int e = lane; e < EMBD; e += 64) {
            eHi[base + e] = 0;
            eLo[base + e] = 0;
        }
    }
}

// ---------------- weight split (separate ih / hh) + bias sum ----------------
__global__ void convw_kernel(const float* __restrict__ Wih,
                             const float* __restrict__ Whh,
                             const float* __restrict__ b_ih,
                             const float* __restrict__ b_hh,
                             unsigned short* __restrict__ ihHi,
                             unsigned short* __restrict__ ihLo,
                             unsigned short* __restrict__ hhHi,
                             unsigned short* __restrict__ hhLo,
                             float* __restrict__ bsum) {
    int j = blockIdx.x; // 0..4095
    if (threadIdx.x == 0) bsum[j] = b_ih[j] + b_hh[j];
    for (int col = threadIdx.x; col < EMBD; col += blockDim.x) {
        unsigned short hi, lo;
        split_bf16(Wih[(size_t)j * EMBD + col], hi, lo);
        ihHi[(size_t)j * EMBD + col] = hi;
        ihLo[(size_t)j * EMBD + col] = lo;
    }
    for (int col = threadIdx.x; col < HID; col += blockDim.x) {
        unsigned short hi, lo;
        split_bf16(Whh[(size_t)j * HID + col], hi, lo);
        hhHi[(size_t)j * HID + col] = hi;
        hhLo[(size_t)j * HID + col] = lo;
    }
}

// ---------------- pre-GEMM: G0s[t][ct][b][32] = emb @ Wih^T + bias ----------
// (3-term bf16, register double-buffered K loop)
__global__ __launch_bounds__(512, 2) void pregemm_kernel(
    const unsigned short* __restrict__ eHi, const unsigned short* __restrict__ eLo,
    const unsigned short* __restrict__ ihHi, const unsigned short* __restrict__ ihLo,
    const float* __restrict__ bsum,
    float* __restrict__ G0s)
{
    int id = blockIdx.x;
    int xcd = id & 7;
    int lid = id >> 3;
    int pc = xcd * 4 + (lid & 3);   // 0..31 col tile (128 gate-cols: 32 jh x 4 g)
    int pm = lid >> 2;              // 0..51 row tile (128 rows)
    int jh0 = pc * 32;
    int m0  = pm * 128;

    int wave = threadIdx.x >> 6;
    int g  = wave & 3;
    int mh = wave >> 2;
    int lane = threadIdx.x & 63;
    int col16 = lane & 15;
    int g4 = lane >> 4;

    f32x4 acc[4][2];
    #pragma unroll
    for (int fm = 0; fm < 4; ++fm)
        #pragma unroll
        for (int fn = 0; fn < 2; ++fn)
            acc[fm][fn] = (f32x4){0.f, 0.f, 0.f, 0.f};

    const unsigned short* aHiP[4];
    const unsigned short* aLoP[4];
    #pragma unroll
    for (int fm = 0; fm < 4; ++fm) {
        size_t row = (size_t)(m0 + mh * 64 + fm * 16 + col16);
        aHiP[fm] = eHi + row * EMBD + 8 * g4;
        aLoP[fm] = eLo + row * EMBD + 8 * g4;
    }
    const unsigned short* bHiP[2];
    const unsigned short* bLoP[2];
    #pragma unroll
    for (int fn = 0; fn < 2; ++fn) {
        size_t row = (size_t)(g * HID + jh0 + fn * 16 + col16);
        bHiP[fn] = ihHi + row * EMBD + 8 * g4;
        bLoP[fn] = ihLo + row * EMBD + 8 * g4;
    }

    short8 rAH[2][4], rAL[2][4], rBH[2][2], rBL[2][2];
    #pragma unroll
    for (int fm = 0; fm < 4; ++fm) {
        rAH[0][fm] = *(const short8*)(aHiP[fm]);
        rAL[0][fm] = *(const short8*)(aLoP[fm]);
    }
    #pragma unroll
    for (int fn = 0; fn < 2; ++fn) {
        rBH[0][fn] = *(const short8*)(bHiP[fn]);
        rBL[0][fn] = *(const short8*)(bLoP[fn]);
    }

    #pragma unroll
    for (int kc = 0; kc < 16; ++kc) {
        const int cur = kc & 1, nxt = cur ^ 1;
        if (kc < 15) {
            int off = (kc + 1) * 32;
            #pragma unroll
            for (int fm = 0; fm < 4; ++fm) {
                rAH[nxt][fm] = *(const short8*)(aHiP[fm] + off);
                rAL[nxt][fm] = *(const short8*)(aLoP[fm] + off);
            }
            #pragma unroll
            for (int fn = 0; fn < 2; ++fn) {
                rBH[nxt][fn] = *(const short8*)(bHiP[fn] + off);
                rBL[nxt][fn] = *(const short8*)(bLoP[fn] + off);
            }
        }
        #pragma unroll
        for (int fm = 0; fm < 4; ++fm)
            #pragma unroll
            for (int fn = 0; fn < 2; ++fn) {
                acc[fm][fn] = __builtin_amdgcn_mfma_f32_16x16x32_bf16(rAH[cur][fm], rBH[cur][fn], acc[fm][fn], 0, 0, 0);
                acc[fm][fn] = __builtin_amdgcn_mfma_f32_16x16x32_bf16(rAH[cur][fm], rBL[cur][fn], acc[fm][fn], 0, 0, 0);
                acc[fm][fn] = __builtin_amdgcn_mfma_f32_16x16x32_bf16(rAL[cur][fm], rBH[cur][fn], acc[fm][fn], 0, 0, 0);
            }
    }

    float bv[2];
    #pragma unroll
    for (int fn = 0; fn < 2; ++fn)
        bv[fn] = bsum[g * HID + jh0 + fn * 16 + col16];

    // write to G0s[t][ct 0..127][b 0..255][cidx 0..31], cidx = g*8 + jj
    #pragma unroll
    for (int fm = 0; fm < 4; ++fm)
        #pragma unroll
        for (int fn = 0; fn < 2; ++fn)
            #pragma unroll
            for (int r = 0; r < 4; ++r) {
                int row = m0 + mh * 64 + fm * 16 + g4 * 4 + r;
                int t = row >> 8, b = row & 255;
                int jhc = jh0 + fn * 16 + col16;
                int ct = jhc >> 3, jj = jhc & 7;
                G0s[(((size_t)t * 128 + ct) * 256 + b) * 32 + g * 8 + jj] =
                    acc[fm][fn][r] + bv[fn];
            }
}

// ---------------- persistent LSTM: Whh in LDS, custom 2-group barrier -------
// 256 blocks x 512 threads, 1 block/CU. mt=0 (blocks 0..127) and mt=1
// (128..255) are independent recurrences with separate barriers.
__global__ __launch_bounds__(512, 2) void lstm_persist(
    const unsigned short* __restrict__ hhHi, const unsigned short* __restrict__ hhLo,
    unsigned short* __restrict__ h0Hi, unsigned short* __restrict__ h0Lo,
    unsigned short* __restrict__ h1Hi, unsigned short* __restrict__ h1Lo,
    const float* __restrict__ G0s,
    float* __restrict__ out,
    unsigned int* __restrict__ barrier)
{
    extern __shared__ char smem[];
    // [0,65536): whh hi, [65536,131072): whh lo, [131072,149504): gbuf[128][36]
    float* gbuf = (float*)(smem + 131072);

    int bx = blockIdx.x;
    int ct = (bx & 7) * 16 + ((bx >> 3) & 15);  // 0..127 (XCD-clustered)
    int mt = bx >> 7;                           // 0..1
    int m0 = mt * 128;
    int jh0 = ct * 8;

    int tid = threadIdx.x;
    int w = tid >> 6;
    int lane = tid & 63;
    int row16 = lane & 15;
    int g4 = lane >> 4;

    unsigned int* barCnt = barrier + mt * 32;       // 128B apart
    unsigned int* barGen = barrier + 64 + mt * 32;

    // ---- stage Whh slice into LDS (once), XOR-swizzled ----
    for (int i = tid; i < 32 * 128; i += 512) {
        int r = i >> 7;
        int byteInRow = (i & 127) << 4;
        int g = r >> 3, jj = r & 7;
        size_t grow = (size_t)(g * HID + jh0 + jj) * HID;
        int dst = r * 2048 + (byteInRow ^ ((r & 7) << 4));
        *(short8*)(smem + dst) =
            *(const short8*)((const char*)(hhHi + grow) + byteInRow);
        *(short8*)(smem + 65536 + dst) =
            *(const short8*)((const char*)(hhLo + grow) + byteInRow);
    }

    // ---- prefetch G0(+bias) for t=0 ----
    float g0v[2][4];
    {
        const float* G0t = G0s + (size_t)ct * (256 * 32);
        #pragma unroll
        for (int u = 0; u < 2; ++u) {
            int idx = tid + u * 512;
            int ml = idx >> 3, jj = idx & 7;
            const float* p = G0t + (size_t)(m0 + ml) * 32 + jj;
            #pragma unroll
            for (int g = 0; g < 4; ++g) g0v[u][g] = p[g * 8];
        }
    }

    float cReg[2] = {0.f, 0.f};
    __syncthreads();

    int bbase = row16 * 2048;
    int bxor = (row16 & 7) << 4;

    for (int t = 0; t < SEQW; ++t) {
        const unsigned short* hInHi = (t & 1) ? h1Hi : h0Hi;
        const unsigned short* hInLo = (t & 1) ? h1Lo : h0Lo;
        unsigned short* hOutHi = (t & 1) ? h0Hi : h1Hi;
        unsigned short* hOutLo = (t & 1) ? h0Lo : h1Lo;

        const unsigned short* aHi = hInHi + (size_t)(m0 + w * 16 + row16) * HID + 8 * g4;
        const unsigned short* aLo = hInLo + (size_t)(m0 + w * 16 + row16) * HID + 8 * g4;

        f32x4 acc0 = {0.f, 0.f, 0.f, 0.f};
        f32x4 acc1 = {0.f, 0.f, 0.f, 0.f};

        // ---- K loop: A register-double-buffered in chunks of 4 k-steps ----
        short8 bufH[2][4], bufL[2][4];
        #pragma unroll
        for (int j = 0; j < 4; ++j) {
            bufH[0][j] = *(const short8*)(aHi + j * 32);
            bufL[0][j] = *(const short8*)(aLo + j * 32);
        }
        #pragma unroll
        for (int c = 0; c < 8; ++c) {
            const int cur = c & 1, nxt = cur ^ 1;
            if (c < 7) {
                #pragma unroll
                for (int j = 0; j < 4; ++j) {
                    bufH[nxt][j] = *(const short8*)(aHi + ((c + 1) * 4 + j) * 32);
                    bufL[nxt][j] = *(const short8*)(aLo + ((c + 1) * 4 + j) * 32);
                }
            }
            #pragma unroll
            for (int j = 0; j < 4; ++j) {
                int kk = c * 4 + j;
                int boff = ((kk * 64 + g4 * 16) ^ bxor);
                short8 bH0 = *(const short8*)(smem + bbase + boff);
                short8 bL0 = *(const short8*)(smem + 65536 + bbase + boff);
                short8 bH1 = *(const short8*)(smem + 32768 + bbase + boff);
                short8 bL1 = *(const short8*)(smem + 65536 + 32768 + bbase + boff);
                acc0 = __builtin_amdgcn_mfma_f32_16x16x32_bf16(bufH[cur][j], bH0, acc0, 0, 0, 0);
                acc0 = __builtin_amdgcn_mfma_f32_16x16x32_bf16(bufH[cur][j], bL0, acc0, 0, 0, 0);
                acc0 = __builtin_amdgcn_mfma_f32_16x16x32_bf16(bufL[cur][j], bH0, acc0, 0, 0, 0);
                acc1 = __builtin_amdgcn_mfma_f32_16x16x32_bf16(bufH[cur][j], bH1, acc1, 0, 0, 0);
                acc1 = __builtin_amdgcn_mfma_f32_16x16x32_bf16(bufH[cur][j], bL1, acc1, 0, 0, 0);
                acc1 = __builtin_amdgcn_mfma_f32_16x16x32_bf16(bufL[cur][j], bH1, acc1, 0, 0, 0);
            }
        }

        // scatter gate partials
        #pragma unroll
        for (int r = 0; r < 4; ++r) {
            gbuf[(w * 16 + g4 * 4 + r) * 36 + row16] = acc0[r];
            gbuf[(w * 16 + g4 * 4 + r) * 36 + 16 + row16] = acc1[r];
        }
        __syncthreads();

        // ---- epilogue: fused gates, c in registers ----
        float g0n[2][4];
        #pragma unroll
        for (int u = 0; u < 2; ++u) {
            int idx = tid + u * 512;
            int ml = idx >> 3, jj = idx & 7;
            float gi  = gbuf[ml * 36 + jj]      + g0v[u][0];
            float gf  = gbuf[ml * 36 + 8 + jj]  + g0v[u][1];
            float gg_ = gbuf[ml * 36 + 16 + jj] + g0v[u][2];
            float go  = gbuf[ml * 36 + 24 + jj] + g0v[u][3];
            float si = 1.0f / (1.0f + expf(-gi));
            float sf = 1.0f / (1.0f + expf(-gf));
            float so = 1.0f / (1.0f + expf(-go));
            float tg = tanhf(gg_);
            float cN = sf * cReg[u] + si * tg;
            float hN = so * tanhf(cN);
            cReg[u] = cN;
            size_t p = (size_t)(m0 + ml) * HID + jh0 + jj;
            if (t == SEQW - 1) {
                out[p] = hN;
            } else {
                unsigned short hh, hl;
                split_bf16(hN, hh, hl);
                hOutHi[p] = hh;
                hOutLo[p] = hl;
            }
        }

        if (t < SEQW - 1) {
            // prefetch next step's G0 (independent of h) - drains during spin
            const float* G0t = G0s + ((size_t)(t + 1) * 128 + ct) * (256 * 32);
            #pragma unroll
            for (int u = 0; u < 2; ++u) {
                int idx = tid + u * 512;
                int ml = idx >> 3, jj = idx & 7;
                const float* p = G0t + (size_t)(m0 + ml) * 32 + jj;
                #pragma unroll
                for (int g = 0; g < 4; ++g) g0n[u][g] = p[g * 8];
            }

            // ---- custom group barrier (monotonic counter) ----
            __syncthreads();              // all h stores complete to L2
            if (tid == 0) {
                __threadfence();          // release: wb L2 to device scope
                unsigned int target = (unsigned int)(t + 1) * GRPBLK;
                unsigned int old = __hip_atomic_fetch_add(
                    barCnt, 1u, __ATOMIC_ACQ_REL, __HIP_MEMORY_SCOPE_AGENT);
                if (old == target - 1) {
                    __hip_atomic_store(barGen, (unsigned int)(t + 1),
                                       __ATOMIC_RELEASE, __HIP_MEMORY_SCOPE_AGENT);
                } else {
                    while (__hip_atomic_load(barGen, __ATOMIC_ACQUIRE,
                                             __HIP_MEMORY_SCOPE_AGENT)
                           < (unsigned int)(t + 1)) {
                        __builtin_amdgcn_s_sleep(1);
                    }
                }
                __threadfence();          // acquire: invalidate L1/L2
            }
            __syncthreads();

            #pragma unroll
            for (int u = 0; u < 2; ++u)
                #pragma unroll
                for (int g = 0; g < 4; ++g) g0v[u][g] = g0n[u][g];
        }
    }
}

extern "C" void kernel_launch(void* const* d_in, const int* in_sizes, int n_in,
                              void* d_out, int out_size, void* d_ws, size_t ws_size,
                              hipStream_t stream) {
    const int*   qv   = (const int*)d_in[0];
    const float* Wemb = (const float*)d_in[2];
    const float* Wih  = (const float*)d_in[3];
    const float* Whh  = (const float*)d_in[4];
    const float* b_ih = (const float*)d_in[5];
    const float* b_hh = (const float*)d_in[6];
    float* out = (float*)d_out;

    char* ws = (char*)d_ws;
    size_t off = 0;
    unsigned short* embHi = (unsigned short*)(ws + off); off += (size_t)MTOT * EMBD * 2;
    unsigned short* embLo = (unsigned short*)(ws + off); off += (size_t)MTOT * EMBD * 2;
    unsigned short* ihHi  = (unsigned short*)(ws + off); off += (size_t)NGATE * EMBD * 2;
    unsigned short* ihLo  = (unsigned short*)(ws + off); off += (size_t)NGATE * EMBD * 2;
    unsigned short* hhHi  = (unsigned short*)(ws + off); off += (size_t)NGATE * HID * 2;
    unsigned short* hhLo  = (unsigned short*)(ws + off); off += (size_t)NGATE * HID * 2;
    unsigned short* h0Hi  = (unsigned short*)(ws + off); off += (size_t)NB * HID * 2;
    unsigned short* h0Lo  = (unsigned short*)(ws + off); off += (size_t)NB * HID * 2;
    unsigned short* h1Hi  = (unsigned short*)(ws + off); off += (size_t)NB * HID * 2;
    unsigned short* h1Lo  = (unsigned short*)(ws + off); off += (size_t)NB * HID * 2;
    float* bsum           = (float*)(ws + off);          off += (size_t)NGATE * 4;
    unsigned int* barrier = (unsigned int*)(ws + off);   off += 512;
    off = (off + 255) & ~(size_t)255;
    float* G0s            = (float*)(ws + off);          off += (size_t)MTOT * NGATE * 4; // 109 MB

    init_kernel<<<NB * HID / 256, 256, 0, stream>>>(h0Hi, h0Lo, barrier);
    embed_kernel<<<MTOT / 4, 256, 0, stream>>>(qv, Wemb, embHi, embLo);
    convw_kernel<<<NGATE, 256, 0, stream>>>(Wih, Whh, b_ih, b_hh,
                                            ihHi, ihLo, hhHi, hhLo, bsum);
    pregemm_kernel<<<1664, 512, 0, stream>>>(embHi, embLo, ihHi, ihLo, bsum, G0s);

    void* kargs[] = {
        (void*)&hhHi, (void*)&hhLo,
        (void*)&h0Hi, (void*)&h0Lo, (void*)&h1Hi, (void*)&h1Lo,
        (void*)&G0s, (void*)&out, (void*)&barrier
    };
    hipLaunchCooperativeKernel((const void*)lstm_persist, dim3(256), dim3(512),
                               kargs, 149504, stream);
}

// Round 7
// 932.373 us; speedup vs baseline: 1.6756x; 1.5928x over previous
//
#include <hip/hip_runtime.h>
#include <hip/hip_bf16.h>

#define VOCAB 50000
#define EMBD  512
#define HID   1024
#define NB    256
#define SEQW  26
#define MTOT  (SEQW * NB)   /* 6656 */
#define NGATE (4 * HID)     /* 4096 */

typedef short short8 __attribute__((ext_vector_type(8)));
typedef _Float16 half8 __attribute__((ext_vector_type(8)));
typedef float f32x4  __attribute__((ext_vector_type(4)));

__device__ __forceinline__ unsigned short f16bits(_Float16 h) {
    union { _Float16 h; unsigned short u; } cv; cv.h = h; return cv.u;
}

__device__ __forceinline__ void split_f16(float x, unsigned short& hi, unsigned short& lo) {
    _Float16 h = (_Float16)x;
    hi = f16bits(h);
    lo = f16bits((_Float16)(x - (float)h));
}

// ---------------- init: zero h slot0 + barrier state ----------------
__global__ void init_kernel(unsigned short* __restrict__ hBuf,
                            unsigned int* __restrict__ bar) {
    int idx = blockIdx.x * blockDim.x + threadIdx.x;  // 1024 blocks x 256
    hBuf[idx] = 0;                                     // slot 0 = h_0 = 0
    if (idx < 1024) bar[idx] = 0;
}

// ---------------- embedding: thread-per-element gather + tanh -> fp16 hi/lo -
__global__ void embed_kernel(const int* __restrict__ qv,
                             const float* __restrict__ Wemb,
                             unsigned short* __restrict__ eHi,
                             unsigned short* __restrict__ eLo) {
    int gid = blockIdx.x * 256 + threadIdx.x;  // over MTOT*EMBD
    int pair = gid >> 9;                       // t*NB + b
    int e = gid & 511;
    int t = pair >> 8, b = pair & 255;
    int tok = qv[b * SEQW + t];
    unsigned short hi = 0, lo = 0;
    if (tok > 0) {
        float x = Wemb[(size_t)e * VOCAB + (tok - 1)];
        float y = tanhf(x);
        split_f16(y, hi, lo);
    }
    eHi[gid] = hi;
    eLo[gid] = lo;
}

// ---------------- weight conversion: ih fp16 hi/lo, hh fp16, bsum -----------
__global__ void convw_kernel(const float* __restrict__ Wih,
                             const float* __restrict__ Whh,
                             const float* __restrict__ b_ih,
                             const float* __restrict__ b_hh,
                             unsigned short* __restrict__ ihHi,
                             unsigned short* __restrict__ ihLo,
                             unsigned short* __restrict__ hh,
                             float* __restrict__ bsum) {
    int j = blockIdx.x; // 0..4095
    if (threadIdx.x == 0) bsum[j] = b_ih[j] + b_hh[j];
    for (int col = threadIdx.x; col < EMBD; col += blockDim.x) {
        unsigned short hi, lo;
        split_f16(Wih[(size_t)j * EMBD + col], hi, lo);
        ihHi[(size_t)j * EMBD + col] = hi;
        ihLo[(size_t)j * EMBD + col] = lo;
    }
    for (int col = threadIdx.x; col < HID; col += blockDim.x) {
        hh[(size_t)j * HID + col] = f16bits((_Float16)Whh[(size_t)j * HID + col]);
    }
}

// ---------------- pre-GEMM: G0n = emb @ Wih^T + bias (3-term fp16) ----------
// G0n layout: [t][ct 0..63][b 0..255][cidx 0..63], cidx = gate*16 + (jh&15),
// ct = jh>>4. 1664 blocks: xcd-interleaved col panels.
__global__ __launch_bounds__(512, 2) void pregemm_kernel(
    const unsigned short* __restrict__ eHi, const unsigned short* __restrict__ eLo,
    const unsigned short* __restrict__ ihHi, const unsigned short* __restrict__ ihLo,
    const float* __restrict__ bsum,
    float* __restrict__ G0n)
{
    int id = blockIdx.x;
    int xcd = id & 7;
    int lid = id >> 3;
    int pc = xcd * 4 + (lid & 3);   // 0..31 col tile (32 jh x 4 gates)
    int pm = lid >> 2;              // 0..51 row tile (128 rows)
    int jh0 = pc * 32;
    int m0  = pm * 128;

    int wave = threadIdx.x >> 6;
    int g  = wave & 3;
    int mh = wave >> 2;
    int lane = threadIdx.x & 63;
    int col16 = lane & 15;
    int g4 = lane >> 4;

    f32x4 acc[4][2];
    #pragma unroll
    for (int fm = 0; fm < 4; ++fm)
        #pragma unroll
        for (int fn = 0; fn < 2; ++fn)
            acc[fm][fn] = (f32x4){0.f, 0.f, 0.f, 0.f};

    const unsigned short* aHiP[4];
    const unsigned short* aLoP[4];
    #pragma unroll
    for (int fm = 0; fm < 4; ++fm) {
        size_t row = (size_t)(m0 + mh * 64 + fm * 16 + col16);
        aHiP[fm] = eHi + row * EMBD + 8 * g4;
        aLoP[fm] = eLo + row * EMBD + 8 * g4;
    }
    const unsigned short* bHiP[2];
    const unsigned short* bLoP[2];
    #pragma unroll
    for (int fn = 0; fn < 2; ++fn) {
        size_t row = (size_t)(g * HID + jh0 + fn * 16 + col16);
        bHiP[fn] = ihHi + row * EMBD + 8 * g4;
        bLoP[fn] = ihLo + row * EMBD + 8 * g4;
    }

    half8 rAH[2][4], rAL[2][4], rBH[2][2], rBL[2][2];
    #pragma unroll
    for (int fm = 0; fm < 4; ++fm) {
        rAH[0][fm] = *(const half8*)(const void*)(aHiP[fm]);
        rAL[0][fm] = *(const half8*)(const void*)(aLoP[fm]);
    }
    #pragma unroll
    for (int fn = 0; fn < 2; ++fn) {
        rBH[0][fn] = *(const half8*)(const void*)(bHiP[fn]);
        rBL[0][fn] = *(const half8*)(const void*)(bLoP[fn]);
    }

    #pragma unroll
    for (int kc = 0; kc < 16; ++kc) {
        const int cur = kc & 1, nxt = cur ^ 1;
        if (kc < 15) {
            int off = (kc + 1) * 32;
            #pragma unroll
            for (int fm = 0; fm < 4; ++fm) {
                rAH[nxt][fm] = *(const half8*)(const void*)(aHiP[fm] + off);
                rAL[nxt][fm] = *(const half8*)(const void*)(aLoP[fm] + off);
            }
            #pragma unroll
            for (int fn = 0; fn < 2; ++fn) {
                rBH[nxt][fn] = *(const half8*)(const void*)(bHiP[fn] + off);
                rBL[nxt][fn] = *(const half8*)(const void*)(bLoP[fn] + off);
            }
        }
        #pragma unroll
        for (int fm = 0; fm < 4; ++fm)
            #pragma unroll
            for (int fn = 0; fn < 2; ++fn) {
                acc[fm][fn] = __builtin_amdgcn_mfma_f32_16x16x32_f16(rAH[cur][fm], rBH[cur][fn], acc[fm][fn], 0, 0, 0);
                acc[fm][fn] = __builtin_amdgcn_mfma_f32_16x16x32_f16(rAH[cur][fm], rBL[cur][fn], acc[fm][fn], 0, 0, 0);
                acc[fm][fn] = __builtin_amdgcn_mfma_f32_16x16x32_f16(rAL[cur][fm], rBH[cur][fn], acc[fm][fn], 0, 0, 0);
            }
    }

    float bv[2];
    #pragma unroll
    for (int fn = 0; fn < 2; ++fn)
        bv[fn] = bsum[g * HID + jh0 + fn * 16 + col16];

    #pragma unroll
    for (int fm = 0; fm < 4; ++fm)
        #pragma unroll
        for (int fn = 0; fn < 2; ++fn)
            #pragma unroll
            for (int r = 0; r < 4; ++r) {
                int row = m0 + mh * 64 + fm * 16 + g4 * 4 + r;
                int t = row >> 8, b = row & 255;
                int jhc = jh0 + fn * 16 + col16;          // 0..1023
                int ct = jhc >> 4, jl = jhc & 15;
                G0n[(((size_t)t * 64 + ct) * 256 + b) * 64 + g * 16 + jl] =
                    acc[fm][fn][r] + bv[fn];
            }
}

// ---------------- persistent LSTM: fp16 1-term, rotating h buffers ----------
// 256 blocks x 512 threads, 1 block/CU (LDS 145KB). Group = 64 blocks on XCD
// pair {2g, 2g+1}: grp = (bx&7)>>1, ct = ((bx>>3)&31) + 32*(bx&1).
// Each group owns batch rows [grp*64, grp*64+64) x all 4096 gate-cols:
// fully independent recurrence, own barrier. h_t lives in slot t of hBuf
// (27 slots) -> readers first-touch-miss L2 (no acquire/invalidate needed);
// writers flush via release-ordered fetch_add (vmcnt drain + wbl2).
// Every 64B h-line is written by 2 blocks of the SAME XCD (ct-pairing).
__global__ __launch_bounds__(512, 2) void lstm_persist(
    const unsigned short* __restrict__ hh,     // fp16 Whh [4096][1024]
    unsigned short* __restrict__ hBuf,         // 27 slots of NB*HID fp16
    const float* __restrict__ G0n,
    float* __restrict__ out,
    unsigned int* __restrict__ bar)
{
    extern __shared__ char smem[];
    // [0, 131072): Whh slice fp16 (64 rows x 2048B, XOR-swizzled)
    // [131072, ...): gbuf[64][66] floats
    float* gbuf = (float*)(smem + 131072);

    int bx = blockIdx.x;
    int grp = (bx & 7) >> 1;                     // 0..3
    int ct  = ((bx >> 3) & 31) + 32 * (bx & 1);  // 0..63
    int m0  = grp * 64;
    int jh0 = ct * 16;

    int tid = threadIdx.x;
    int w = tid >> 6;
    int gate = w & 3, mh = w >> 2;
    int lane = tid & 63;
    int col16 = lane & 15, g4 = lane >> 4;

    unsigned int* cnt = bar + grp * 64;
    unsigned int* gen = bar + 512 + grp * 64;

    // ---- stage Whh gate-rows into LDS (once), XOR-swizzled ----
    // lds row r = gate*16 + jl  <->  Whh row gate*HID + jh0 + jl
    const char* hhB = (const char*)hh;
    for (int i = tid; i < 64 * 128; i += 512) {
        int r = i >> 7;
        int byteInRow = (i & 127) << 4;
        size_t grow = (size_t)((r >> 4) * HID + jh0 + (r & 15)) * HID * 2;
        int dst = r * 2048 + (byteInRow ^ ((r & 7) << 4));
        *(short8*)(smem + dst) = *(const short8*)(hhB + grow + byteInRow);
    }

    // ---- G0 prefetch for t=0 ----
    float g0v[2][4];
    #pragma unroll
    for (int u = 0; u < 2; ++u) {
        int idx = tid + u * 512;
        int ml = idx >> 4, jl = idx & 15;
        const float* p = G0n + (((size_t)0 * 64 + ct) * 256 + (m0 + ml)) * 64 + jl;
        #pragma unroll
        for (int q = 0; q < 4; ++q) g0v[u][q] = p[q * 16];
    }

    float cReg[2] = {0.f, 0.f};
    __syncthreads();

    int bbase = (gate * 16 + col16) * 2048;
    int bxor = (col16 & 7) << 4;

    for (int t = 0; t < SEQW; ++t) {
        const unsigned short* hIn = hBuf + (size_t)t * NB * HID;
        unsigned short* hOut = hBuf + (size_t)(t + 1) * NB * HID;

        const unsigned short* r0 = hIn + (size_t)(m0 + mh * 32 + col16) * HID + 8 * g4;
        const unsigned short* r1 = r0 + (size_t)16 * HID;

        f32x4 acc0 = {0.f, 0.f, 0.f, 0.f};
        f32x4 acc1 = {0.f, 0.f, 0.f, 0.f};

        // ---- K loop: single-term fp16, A chunk-double-buffered ----
        half8 aA[2][4], aB[2][4];
        #pragma unroll
        for (int j = 0; j < 4; ++j) {
            aA[0][j] = *(const half8*)(const void*)(r0 + j * 32);
            aB[0][j] = *(const half8*)(const void*)(r1 + j * 32);
        }
        #pragma unroll
        for (int c = 0; c < 8; ++c) {
            const int cur = c & 1, nxt = cur ^ 1;
            if (c < 7) {
                #pragma unroll
                for (int j = 0; j < 4; ++j) {
                    aA[nxt][j] = *(const half8*)(const void*)(r0 + ((c + 1) * 4 + j) * 32);
                    aB[nxt][j] = *(const half8*)(const void*)(r1 + ((c + 1) * 4 + j) * 32);
                }
            }
            #pragma unroll
            for (int j = 0; j < 4; ++j) {
                int kk = c * 4 + j;
                int boff = ((kk * 64 + g4 * 16) ^ bxor);
                half8 bf = *(const half8*)(const void*)(smem + bbase + boff);
                acc0 = __builtin_amdgcn_mfma_f32_16x16x32_f16(aA[cur][j], bf, acc0, 0, 0, 0);
                acc1 = __builtin_amdgcn_mfma_f32_16x16x32_f16(aB[cur][j], bf, acc1, 0, 0, 0);
            }
        }

        // scatter: out row = mh*32 + mf*16 + g4*4 + r, col = gate*16 + col16
        #pragma unroll
        for (int r = 0; r < 4; ++r) {
            gbuf[(mh * 32 + g4 * 4 + r) * 66 + gate * 16 + col16] = acc0[r];
            gbuf[(mh * 32 + 16 + g4 * 4 + r) * 66 + gate * 16 + col16] = acc1[r];
        }
        __syncthreads();

        // ---- epilogue: 2 cells/thread, c in registers ----
        #pragma unroll
        for (int u = 0; u < 2; ++u) {
            int idx = tid + u * 512;
            int ml = idx >> 4, jl = idx & 15;
            float gi  = gbuf[ml * 66 + jl]      + g0v[u][0];
            float gf  = gbuf[ml * 66 + 16 + jl] + g0v[u][1];
            float gg_ = gbuf[ml * 66 + 32 + jl] + g0v[u][2];
            float go  = gbuf[ml * 66 + 48 + jl] + g0v[u][3];
            float si = 1.0f / (1.0f + expf(-gi));
            float sf = 1.0f / (1.0f + expf(-gf));
            float so = 1.0f / (1.0f + expf(-go));
            float tg = tanhf(gg_);
            float cN = sf * cReg[u] + si * tg;
            float hN = so * tanhf(cN);
            cReg[u] = cN;
            size_t p = (size_t)(m0 + ml) * HID + jh0 + jl;
            if (t == SEQW - 1) out[p] = hN;
            else               hOut[p] = f16bits((_Float16)hN);
        }

        if (t < SEQW - 1) {
            // prefetch next step's G0 (independent of h)
            #pragma unroll
            for (int u = 0; u < 2; ++u) {
                int idx = tid + u * 512;
                int ml = idx >> 4, jl = idx & 15;
                const float* p = G0n + (((size_t)(t + 1) * 64 + ct) * 256 + (m0 + ml)) * 64 + jl;
                #pragma unroll
                for (int q = 0; q < 4; ++q) g0v[u][q] = p[q * 16];
            }

            // ---- group barrier: release arrival, relaxed poll, no acquire --
            __syncthreads();   // drains each wave's stores (vmcnt 0)
            if (tid == 0) {
                unsigned int target = (unsigned int)(t + 1) * 64u;
                unsigned int old = __hip_atomic_fetch_add(
                    cnt, 1u, __ATOMIC_RELEASE, __HIP_MEMORY_SCOPE_AGENT);
                if (old == target - 1) {
                    __hip_atomic_store(gen, (unsigned int)(t + 1),
                                       __ATOMIC_RELEASE, __HIP_MEMORY_SCOPE_AGENT);
                } else {
                    while (__hip_atomic_load(gen, __ATOMIC_RELAXED,
                                             __HIP_MEMORY_SCOPE_AGENT)
                           < (unsigned int)(t + 1)) {
                        __builtin_amdgcn_s_sleep(2);
                    }
                }
            }
            __syncthreads();
        }
    }
}

extern "C" void kernel_launch(void* const* d_in, const int* in_sizes, int n_in,
                              void* d_out, int out_size, void* d_ws, size_t ws_size,
                              hipStream_t stream) {
    const int*   qv   = (const int*)d_in[0];
    const float* Wemb = (const float*)d_in[2];
    const float* Wih  = (const float*)d_in[3];
    const float* Whh  = (const float*)d_in[4];
    const float* b_ih = (const float*)d_in[5];
    const float* b_hh = (const float*)d_in[6];
    float* out = (float*)d_out;

    char* ws = (char*)d_ws;
    size_t off = 0;
    unsigned short* eHi  = (unsigned short*)(ws + off); off += (size_t)MTOT * EMBD * 2;
    unsigned short* eLo  = (unsigned short*)(ws + off); off += (size_t)MTOT * EMBD * 2;
    unsigned short* ihHi = (unsigned short*)(ws + off); off += (size_t)NGATE * EMBD * 2;
    unsigned short* ihLo = (unsigned short*)(ws + off); off += (size_t)NGATE * EMBD * 2;
    unsigned short* hh   = (unsigned short*)(ws + off); off += (size_t)NGATE * HID * 2;
    unsigned short* hBuf = (unsigned short*)(ws + off); off += (size_t)(SEQW + 1) * NB * HID * 2;
    float* bsum          = (float*)(ws + off);          off += (size_t)NGATE * 4;
    unsigned int* bar    = (unsigned int*)(ws + off);   off += 4096;
    off = (off + 255) & ~(size_t)255;
    float* G0n           = (float*)(ws + off);          off += (size_t)MTOT * NGATE * 4; // 109 MB

    init_kernel<<<NB * HID / 256, 256, 0, stream>>>(hBuf, bar);
    embed_kernel<<<MTOT * EMBD / 256, 256, 0, stream>>>(qv, Wemb, eHi, eLo);
    convw_kernel<<<NGATE, 256, 0, stream>>>(Wih, Whh, b_ih, b_hh, ihHi, ihLo, hh, bsum);
    pregemm_kernel<<<1664, 512, 0, stream>>>(eHi, eLo, ihHi, ihLo, bsum, G0n);

    lstm_persist<<<256, 512, 147968, stream>>>(hh, hBuf, G0n, out, bar);
}

// Round 8
// 686.962 us; speedup vs baseline: 2.2742x; 1.3572x over previous
//
#include <hip/hip_runtime.h>
#include <hip/hip_bf16.h>

#define VOCAB 50000
#define EMBD  512
#define HID   1024
#define NB    256
#define SEQW  26
#define MTOT  (SEQW * NB)   /* 6656 */
#define NGATE (4 * HID)     /* 4096 */

typedef short short8 __attribute__((ext_vector_type(8)));
typedef _Float16 half8 __attribute__((ext_vector_type(8)));
typedef float f32x4  __attribute__((ext_vector_type(4)));
typedef float f32x2  __attribute__((ext_vector_type(2)));

__device__ __forceinline__ unsigned short f16bits(_Float16 h) {
    union { _Float16 h; unsigned short u; } cv; cv.h = h; return cv.u;
}

// ---------------- init: zero h slot0 + barrier state ----------------
__global__ void init_kernel(unsigned short* __restrict__ hBuf,
                            unsigned int* __restrict__ bar) {
    int idx = blockIdx.x * blockDim.x + threadIdx.x;  // 1024 blocks x 256
    hBuf[idx] = 0;                                     // slot 0 = h_0 = 0
    if (idx < 1024) bar[idx] = 0;
}

// ---------------- embedding: thread-per-element gather + tanh -> fp16 -------
__global__ void embed_kernel(const int* __restrict__ qv,
                             const float* __restrict__ Wemb,
                             unsigned short* __restrict__ eHi) {
    int gid = blockIdx.x * 256 + threadIdx.x;  // over MTOT*EMBD
    int pair = gid >> 9;                       // t*NB + b
    int e = gid & 511;
    int t = pair >> 8, b = pair & 255;
    int tok = qv[b * SEQW + t];
    unsigned short hi = 0;
    if (tok > 0) {
        float x = Wemb[(size_t)e * VOCAB + (tok - 1)];
        hi = f16bits((_Float16)tanhf(x));
    }
    eHi[gid] = hi;
}

// ---------------- weight conversion: ih fp16, hh fp16, bsum -----------------
__global__ void convw_kernel(const float* __restrict__ Wih,
                             const float* __restrict__ Whh,
                             const float* __restrict__ b_ih,
                             const float* __restrict__ b_hh,
                             unsigned short* __restrict__ ih,
                             unsigned short* __restrict__ hh,
                             float* __restrict__ bsum) {
    int j = blockIdx.x; // 0..4095
    if (threadIdx.x == 0) bsum[j] = b_ih[j] + b_hh[j];
    for (int col = threadIdx.x; col < EMBD; col += blockDim.x)
        ih[(size_t)j * EMBD + col] = f16bits((_Float16)Wih[(size_t)j * EMBD + col]);
    for (int col = threadIdx.x; col < HID; col += blockDim.x)
        hh[(size_t)j * HID + col] = f16bits((_Float16)Whh[(size_t)j * HID + col]);
}

// ---------------- pre-GEMM: G0n = emb @ Wih^T + bias (1-term fp16) ----------
// G0n layout: [t][ct 0..63][b 0..255][cidx 0..63], cidx = gate*16 + (jh&15),
// ct = jh>>4. 1664 blocks: xcd-interleaved col panels.
__global__ __launch_bounds__(512, 2) void pregemm_kernel(
    const unsigned short* __restrict__ eHi,
    const unsigned short* __restrict__ ih,
    const float* __restrict__ bsum,
    float* __restrict__ G0n)
{
    int id = blockIdx.x;
    int xcd = id & 7;
    int lid = id >> 3;
    int pc = xcd * 4 + (lid & 3);   // 0..31 col tile (32 jh x 4 gates)
    int pm = lid >> 2;              // 0..51 row tile (128 rows)
    int jh0 = pc * 32;
    int m0  = pm * 128;

    int wave = threadIdx.x >> 6;
    int g  = wave & 3;
    int mh = wave >> 2;
    int lane = threadIdx.x & 63;
    int col16 = lane & 15;
    int g4 = lane >> 4;

    f32x4 acc[4][2];
    #pragma unroll
    for (int fm = 0; fm < 4; ++fm)
        #pragma unroll
        for (int fn = 0; fn < 2; ++fn)
            acc[fm][fn] = (f32x4){0.f, 0.f, 0.f, 0.f};

    const unsigned short* aP[4];
    #pragma unroll
    for (int fm = 0; fm < 4; ++fm)
        aP[fm] = eHi + (size_t)(m0 + mh * 64 + fm * 16 + col16) * EMBD + 8 * g4;
    const unsigned short* bP[2];
    #pragma unroll
    for (int fn = 0; fn < 2; ++fn)
        bP[fn] = ih + (size_t)(g * HID + jh0 + fn * 16 + col16) * EMBD + 8 * g4;

    half8 rA[2][4], rB[2][2];
    #pragma unroll
    for (int fm = 0; fm < 4; ++fm) rA[0][fm] = *(const half8*)(const void*)(aP[fm]);
    #pragma unroll
    for (int fn = 0; fn < 2; ++fn) rB[0][fn] = *(const half8*)(const void*)(bP[fn]);

    #pragma unroll
    for (int kc = 0; kc < 16; ++kc) {
        const int cur = kc & 1, nxt = cur ^ 1;
        if (kc < 15) {
            int off = (kc + 1) * 32;
            #pragma unroll
            for (int fm = 0; fm < 4; ++fm)
                rA[nxt][fm] = *(const half8*)(const void*)(aP[fm] + off);
            #pragma unroll
            for (int fn = 0; fn < 2; ++fn)
                rB[nxt][fn] = *(const half8*)(const void*)(bP[fn] + off);
        }
        #pragma unroll
        for (int fm = 0; fm < 4; ++fm)
            #pragma unroll
            for (int fn = 0; fn < 2; ++fn)
                acc[fm][fn] = __builtin_amdgcn_mfma_f32_16x16x32_f16(
                    rA[cur][fm], rB[cur][fn], acc[fm][fn], 0, 0, 0);
    }

    float bv[2];
    #pragma unroll
    for (int fn = 0; fn < 2; ++fn)
        bv[fn] = bsum[g * HID + jh0 + fn * 16 + col16];

    #pragma unroll
    for (int fm = 0; fm < 4; ++fm)
        #pragma unroll
        for (int fn = 0; fn < 2; ++fn)
            #pragma unroll
            for (int r = 0; r < 4; ++r) {
                int row = m0 + mh * 64 + fm * 16 + g4 * 4 + r;
                int t = row >> 8, b = row & 255;
                int jhc = jh0 + fn * 16 + col16;          // 0..1023
                int ct = jhc >> 4, jl = jhc & 15;
                G0n[(((size_t)t * 64 + ct) * 256 + b) * 64 + g * 16 + jl] =
                    acc[fm][fn][r] + bv[fn];
            }
}

// ---------------- persistent LSTM: fp16 1-term, sc1 h-exchange --------------
// 256 blocks x 512 threads, 1 block/CU. Group = 64 blocks (grp=(bx&7)>>1):
// batch rows [grp*64, +64) x all 4096 gate-cols; own barrier.
// h_t in slot t of hBuf (27 slots). Writers: agent-scope RELAXED u32 stores
// (sc1 -> write-through to L3 = coherence point); syncthreads drains vmcnt
// before the RELAXED arrival add -> no release/wbl2, no acquire/invalidate.
// Readers: slot lines first-touched after the barrier -> L3-fresh.
__global__ __launch_bounds__(512, 1) void lstm_persist(
    const unsigned short* __restrict__ hh,     // fp16 Whh [4096][1024]
    unsigned short* __restrict__ hBuf,         // 27 slots of NB*HID fp16
    const float* __restrict__ G0n,
    float* __restrict__ out,
    unsigned int* __restrict__ bar)
{
    extern __shared__ char smem[];
    // [0, 131072): Whh slice fp16 (64 rows x 2048B, XOR-swizzled)
    // [131072, ...): gbuf[64][66] floats
    float* gbuf = (float*)(smem + 131072);

    int bx = blockIdx.x;
    int grp = (bx & 7) >> 1;                     // 0..3
    int ct  = ((bx >> 3) & 31) + 32 * (bx & 1);  // 0..63
    int m0  = grp * 64;
    int jh0 = ct * 16;

    int tid = threadIdx.x;
    int w = tid >> 6;
    int gate = w & 3, mh = w >> 2;
    int lane = tid & 63;
    int col16 = lane & 15, g4 = lane >> 4;

    unsigned int* cnt = bar + grp * 64;
    unsigned int* gen = bar + 512 + grp * 64;

    // ---- stage Whh gate-rows into LDS (once), XOR-swizzled ----
    const char* hhB = (const char*)hh;
    for (int i = tid; i < 64 * 128; i += 512) {
        int r = i >> 7;
        int byteInRow = (i & 127) << 4;
        size_t grow = (size_t)((r >> 4) * HID + jh0 + (r & 15)) * HID * 2;
        int dst = r * 2048 + (byteInRow ^ ((r & 7) << 4));
        *(short8*)(smem + dst) = *(const short8*)(hhB + grow + byteInRow);
    }

    // epilogue mapping: thread owns (ml = tid>>3, jl = 2*(tid&7), +1)
    int ml = tid >> 3, jlp = tid & 7;

    // ---- G0 prefetch for t=0 (float2 per gate) ----
    f32x2 g0v[4];
    {
        const float* p = G0n + (((size_t)ct) * 256 + (m0 + ml)) * 64 + 2 * jlp;
        #pragma unroll
        for (int q = 0; q < 4; ++q) g0v[q] = *(const f32x2*)(p + q * 16);
    }

    float cReg[2] = {0.f, 0.f};
    __syncthreads();

    int bbase = (gate * 16 + col16) * 2048;
    int bxor = (col16 & 7) << 4;

    for (int t = 0; t < SEQW; ++t) {
        const unsigned short* hIn = hBuf + (size_t)t * NB * HID;
        unsigned short* hOut = hBuf + (size_t)(t + 1) * NB * HID;

        const unsigned short* r0 = hIn + (size_t)(m0 + mh * 32 + col16) * HID + 8 * g4;
        const unsigned short* r1 = r0 + (size_t)16 * HID;

        f32x4 acc0 = {0.f, 0.f, 0.f, 0.f};
        f32x4 acc1 = {0.f, 0.f, 0.f, 0.f};

        // ---- K loop in 2 halves; 32 loads issued straight-line per half ----
        #pragma unroll
        for (int hf = 0; hf < 2; ++hf) {
            half8 aA[16], aB[16];
            #pragma unroll
            for (int k = 0; k < 16; ++k) {
                aA[k] = *(const half8*)(const void*)(r0 + (hf * 16 + k) * 32);
                aB[k] = *(const half8*)(const void*)(r1 + (hf * 16 + k) * 32);
            }
            #pragma unroll
            for (int k = 0; k < 16; ++k) {
                int kk = hf * 16 + k;
                int boff = ((kk * 64 + g4 * 16) ^ bxor);
                half8 bf = *(const half8*)(const void*)(smem + bbase + boff);
                acc0 = __builtin_amdgcn_mfma_f32_16x16x32_f16(aA[k], bf, acc0, 0, 0, 0);
                acc1 = __builtin_amdgcn_mfma_f32_16x16x32_f16(aB[k], bf, acc1, 0, 0, 0);
            }
        }

        // scatter: local row = mh*32 + (0|16) + g4*4 + r, col = gate*16 + col16
        #pragma unroll
        for (int r = 0; r < 4; ++r) {
            gbuf[(mh * 32 + g4 * 4 + r) * 66 + gate * 16 + col16] = acc0[r];
            gbuf[(mh * 32 + 16 + g4 * 4 + r) * 66 + gate * 16 + col16] = acc1[r];
        }
        __syncthreads();

        // ---- epilogue: 2 adjacent cells/thread ----
        float hN[2];
        #pragma unroll
        for (int u = 0; u < 2; ++u) {
            int jl = 2 * jlp + u;
            float gi  = gbuf[ml * 66 + jl]      + g0v[0][u];
            float gf  = gbuf[ml * 66 + 16 + jl] + g0v[1][u];
            float gg_ = gbuf[ml * 66 + 32 + jl] + g0v[2][u];
            float go  = gbuf[ml * 66 + 48 + jl] + g0v[3][u];
            float si = 1.0f / (1.0f + expf(-gi));
            float sf = 1.0f / (1.0f + expf(-gf));
            float so = 1.0f / (1.0f + expf(-go));
            float tg = tanhf(gg_);
            float cN = sf * cReg[u] + si * tg;
            hN[u] = so * tanhf(cN);
            cReg[u] = cN;
        }
        size_t p = (size_t)(m0 + ml) * HID + jh0 + 2 * jlp;
        if (t == SEQW - 1) {
            *(f32x2*)(out + p) = (f32x2){hN[0], hN[1]};
        } else {
            unsigned int hv = (unsigned int)f16bits((_Float16)hN[0]) |
                              ((unsigned int)f16bits((_Float16)hN[1]) << 16);
            __hip_atomic_store((unsigned int*)(hOut + p), hv,
                               __ATOMIC_RELAXED, __HIP_MEMORY_SCOPE_AGENT);

            // prefetch next step's G0 (read-only, independent of h)
            const float* pg = G0n + (((size_t)(t + 1) * 64 + ct) * 256 + (m0 + ml)) * 64 + 2 * jlp;
            #pragma unroll
            for (int q = 0; q < 4; ++q) g0v[q] = *(const f32x2*)(pg + q * 16);

            // ---- group barrier: all-relaxed (data already at L3 via sc1) ---
            __syncthreads();   // drains vmcnt: h stores acked at L3
            if (tid == 0) {
                unsigned int t1 = (unsigned int)(t + 1);
                unsigned int old = __hip_atomic_fetch_add(
                    cnt, 1u, __ATOMIC_RELAXED, __HIP_MEMORY_SCOPE_AGENT);
                if (old == t1 * 64u - 1u) {
                    __hip_atomic_store(gen, t1, __ATOMIC_RELAXED,
                                       __HIP_MEMORY_SCOPE_AGENT);
                } else {
                    while (__hip_atomic_load(gen, __ATOMIC_RELAXED,
                                             __HIP_MEMORY_SCOPE_AGENT) < t1) {
                        __builtin_amdgcn_s_sleep(1);
                    }
                }
            }
            __syncthreads();
        }
    }
}

extern "C" void kernel_launch(void* const* d_in, const int* in_sizes, int n_in,
                              void* d_out, int out_size, void* d_ws, size_t ws_size,
                              hipStream_t stream) {
    const int*   qv   = (const int*)d_in[0];
    const float* Wemb = (const float*)d_in[2];
    const float* Wih  = (const float*)d_in[3];
    const float* Whh  = (const float*)d_in[4];
    const float* b_ih = (const float*)d_in[5];
    const float* b_hh = (const float*)d_in[6];
    float* out = (float*)d_out;

    char* ws = (char*)d_ws;
    size_t off = 0;
    unsigned short* eHi  = (unsigned short*)(ws + off); off += (size_t)MTOT * EMBD * 2;
    unsigned short* ih   = (unsigned short*)(ws + off); off += (size_t)NGATE * EMBD * 2;
    unsigned short* hh   = (unsigned short*)(ws + off); off += (size_t)NGATE * HID * 2;
    unsigned short* hBuf = (unsigned short*)(ws + off); off += (size_t)(SEQW + 1) * NB * HID * 2;
    float* bsum          = (float*)(ws + off);          off += (size_t)NGATE * 4;
    unsigned int* bar    = (unsigned int*)(ws + off);   off += 4096;
    off = (off + 255) & ~(size_t)255;
    float* G0n           = (float*)(ws + off);          off += (size_t)MTOT * NGATE * 4; // 109 MB

    init_kernel<<<NB * HID / 256, 256, 0, stream>>>(hBuf, bar);
    embed_kernel<<<MTOT * EMBD / 256, 256, 0, stream>>>(qv, Wemb, eHi);
    convw_kernel<<<NGATE, 256, 0, stream>>>(Wih, Whh, b_ih, b_hh, ih, hh, bsum);
    pregemm_kernel<<<1664, 512, 0, stream>>>(eHi, ih, bsum, G0n);

    lstm_persist<<<256, 512, 147968, stream>>>(hh, hBuf, G0n, out, bar);
}